// Round 16
// baseline (81.027 us; speedup 1.0000x reference)
//
#include <hip/hip_runtime.h>
#include <hip/hip_bf16.h>

#define BS    256
#define PIX   1024
#define CBAND 200
#define NK    7            // K-steps of 32 (K 200 -> 224; tail k>=200 hits B=0)
#define FEAT  64
#define ALPHA 0.2f
#define BETA  0.5f

typedef __attribute__((ext_vector_type(8))) short bf16x8;   // MFMA A/B fragment
typedef __attribute__((ext_vector_type(4))) float f32x4;    // MFMA C/D fragment

__device__ __forceinline__ float lrelu(float v) { return v >= 0.f ? v : ALPHA * v; }
__device__ __forceinline__ float bf2f(short s) {
    unsigned int u = ((unsigned int)(unsigned short)s) << 16;
    return __uint_as_float(u);
}
__device__ __forceinline__ unsigned int pkbf(float a, float b) {
    __hip_bfloat162 t = __float22bfloat162_rn(make_float2(a, b));
    return *(unsigned int*)&t;
}

// ---------------------------------------------------------------------------
// Kernel 0 (fused prep), 256 threads/block.  (R9 form, unchanged)
// Blocks 0..13: pack Wk||Wv into bf16 B-fragments (zero for k>=200).
// Blocks 14..269: central-pixel features (fp32 exact), K split 4 ways.
// ---------------------------------------------------------------------------
__global__ __launch_bounds__(256) void prep_k(
    const float* __restrict__ x, const float* __restrict__ Wk,
    const float* __restrict__ Wv, const float* __restrict__ Wn,
    unsigned short* __restrict__ Wb, float* __restrict__ c1,
    float* __restrict__ chalf)
{
    const int tid = threadIdx.x;
    if (blockIdx.x < 14) {
        int bid2 = blockIdx.x * 4 + (tid >> 6);   // 0..55
        int l  = tid & 63;
        int nf = bid2 & 7;
        int ks = bid2 >> 3;
        int c  = nf * 16 + (l & 15);
        int k0 = ks * 32 + (l >> 4) * 8;
        __attribute__((aligned(16))) unsigned short o[8];
        #pragma unroll
        for (int i = 0; i < 8; ++i) {
            int k = k0 + i;
            float w = 0.f;
            if (k < CBAND) w = (c < 64) ? Wk[k * 64 + c] : Wv[k * 64 + (c - 64)];
            unsigned int u = __float_as_uint(w);
            u += 0x7FFFu + ((u >> 16) & 1u);      // RNE to bf16
            o[i] = (unsigned short)(u >> 16);
        }
        *(uint4*)&Wb[((size_t)bid2 * 64 + l) * 8] = *(uint4*)o;
        return;
    }
    __shared__ float xr[CBAND];
    __shared__ float part[2][4][FEAT];
    __shared__ float c2s[FEAT];
    int b = blockIdx.x - 14;
    int f = tid & 63, q = tid >> 6;
    const float* xc = x + (size_t)b * (PIX * CBAND) + (16 * 32 + 16) * CBAND;
    for (int c = tid; c < CBAND; c += 256) xr[c] = xc[c];
    __syncthreads();
    float a1 = 0.f, a2 = 0.f;
    #pragma unroll 5
    for (int c = q * 50; c < q * 50 + 50; ++c) {
        float xv = xr[c];
        a1 += xv * Wk[c * FEAT + f];
        a2 += xv * Wv[c * FEAT + f];
    }
    part[0][q][f] = a1;
    part[1][q][f] = a2;
    __syncthreads();
    if (tid < FEAT) {
        float s1 = part[0][0][f] + part[0][1][f] + part[0][2][f] + part[0][3][f];
        float s2 = part[1][0][f] + part[1][1][f] + part[1][2][f] + part[1][3][f];
        c1[b * FEAT + f] = lrelu(s1);
        c2s[f] = lrelu(s2);
    }
    __syncthreads();
    if (tid < FEAT) {
        float a3 = 0.f;
        #pragma unroll 8
        for (int g = 0; g < FEAT; ++g) a3 += c2s[g] * Wn[f * FEAT + g];
        chalf[b * FEAT + f] = BETA * lrelu(a3);
    }
}

// ---------------------------------------------------------------------------
// Kernel 1: DIRECT-FRAGMENT MFMA GEMM — no LDS, no barriers, independent waves.
// Block = 4 waves, 64 rows. Wave w: kind=(w&1) (0=h1/Wk, 1=h2/Wv), rows
// rowbase = blk*64 + (w>>1)*32. Each wave computes ALL 64 cols of its kind
// for its 32 rows: 2(mi) x 4(nj) x 7(ks) MFMA.
//  - A-fragments loaded per-lane straight from global fp32 x (one 128B line
//    per row per ks, fully consumed -> no over-fetch), cvt to bf16 in-reg.
//  - B-fragments from prepped Wb (L1/L2-hot), double-buffered per ks.
//  - h1 waves use SWAPPED mfma(W,x): f on reg axis -> f-dot with c1 is 16
//    in-reg FMAs + shfl(16,32); direct mcT store. No cross-wave anything.
//  - h2 waves unswapped: p on reg axis -> packed bf16 uint2 stores.
//  - ks=6 tail: g4>=1 lanes clamp addr to row start (in-bounds); those k>=200
//    products are killed by B=0 (x garbage is finite, 0*x=0).
// ---------------------------------------------------------------------------
__global__ __launch_bounds__(256) void gemm_direct(
    const float* __restrict__ x, const unsigned short* __restrict__ Wb,
    const float* __restrict__ c1, float* __restrict__ mcT,
    unsigned short* __restrict__ h2)
{
    const int tid  = threadIdx.x;
    const int l    = tid & 63;
    const int w    = tid >> 6;
    const int fr   = l & 15;
    const int g4   = l >> 4;
    const int kind = w & 1;                       // 0 = h1, 1 = h2
    const int blk0 = blockIdx.x * 64;
    const int rowbase = blk0 + (w >> 1) * 32;
    const int bb   = blk0 >> 10;                  // 64 | 1024
    const int pb   = rowbase & (PIX - 1);

    const bf16x8* wbv = (const bf16x8*)Wb;
    const int nf0 = kind ? 4 : 0;

    // h1 waves: c1 slice to regs (swapped-D: reg r of frag nj <-> f=nj*16+g4*4+r)
    float c1r[4][4];
    if (!kind) {
        #pragma unroll
        for (int nj = 0; nj < 4; ++nj)
            #pragma unroll
            for (int r = 0; r < 4; ++r)
                c1r[nj][r] = c1[bb * FEAT + nj * 16 + g4 * 4 + r];
    }

    const float* xrow0 = x + (size_t)(rowbase + fr) * CBAND;
    const float* xrow1 = x + (size_t)(rowbase + 16 + fr) * CBAND;

    f32x4 xa[2][2][2];                            // [buf][mi][half]
    auto loadA = [&](int ks, int buf) {
        int kofs = ks * 32 + g4 * 8;
        if (ks == 6 && g4 != 0) kofs = 0;         // clamp tail; B=0 kills it
        xa[buf][0][0] = *(const f32x4*)(xrow0 + kofs);
        xa[buf][0][1] = *(const f32x4*)(xrow0 + kofs + 4);
        xa[buf][1][0] = *(const f32x4*)(xrow1 + kofs);
        xa[buf][1][1] = *(const f32x4*)(xrow1 + kofs + 4);
    };

    bf16x8 bq[2][4];
    #pragma unroll
    for (int nj = 0; nj < 4; ++nj) bq[0][nj] = wbv[(nf0 + nj) * 64 + l];
    loadA(0, 0);

    f32x4 acc[2][4];
    #pragma unroll
    for (int mi = 0; mi < 2; ++mi)
        #pragma unroll
        for (int nj = 0; nj < 4; ++nj) acc[mi][nj] = (f32x4){0.f, 0.f, 0.f, 0.f};

    #pragma unroll
    for (int ks = 0; ks < NK; ++ks) {
        int buf = ks & 1;
        if (ks + 1 < NK) {                        // prefetch next ks
            #pragma unroll
            for (int nj = 0; nj < 4; ++nj)
                bq[buf ^ 1][nj] = wbv[((ks + 1) * 8 + nf0 + nj) * 64 + l];
            loadA(ks + 1, buf ^ 1);
        }
        bf16x8 a[2];
        #pragma unroll
        for (int mi = 0; mi < 2; ++mi) {
            f32x4 lo = xa[buf][mi][0];
            f32x4 hi = xa[buf][mi][1];
            union { bf16x8 v; unsigned int u[4]; } af;
            af.u[0] = pkbf(lo[0], lo[1]);
            af.u[1] = pkbf(lo[2], lo[3]);
            af.u[2] = pkbf(hi[0], hi[1]);
            af.u[3] = pkbf(hi[2], hi[3]);
            a[mi] = af.v;
        }
        if (!kind) {                              // h1: swapped operands
            #pragma unroll
            for (int nj = 0; nj < 4; ++nj) {
                acc[0][nj] = __builtin_amdgcn_mfma_f32_16x16x32_bf16(bq[buf][nj], a[0], acc[0][nj], 0, 0, 0);
                acc[1][nj] = __builtin_amdgcn_mfma_f32_16x16x32_bf16(bq[buf][nj], a[1], acc[1][nj], 0, 0, 0);
            }
        } else {                                  // h2: unswapped
            #pragma unroll
            for (int nj = 0; nj < 4; ++nj) {
                acc[0][nj] = __builtin_amdgcn_mfma_f32_16x16x32_bf16(a[0], bq[buf][nj], acc[0][nj], 0, 0, 0);
                acc[1][nj] = __builtin_amdgcn_mfma_f32_16x16x32_bf16(a[1], bq[buf][nj], acc[1][nj], 0, 0, 0);
            }
        }
    }

    if (!kind) {
        // h1 epilogue: 16 in-reg FMAs + shfl(16,32); g4==0 lanes store mcT
        #pragma unroll
        for (int mi = 0; mi < 2; ++mi) {
            float part = 0.f;
            #pragma unroll
            for (int nj = 0; nj < 4; ++nj)
                #pragma unroll
                for (int r = 0; r < 4; ++r)
                    part += lrelu(acc[mi][nj][r]) * c1r[nj][r];
            part += __shfl_xor(part, 16);
            part += __shfl_xor(part, 32);
            if (g4 == 0) {
                int p = pb + mi * 16 + fr;
                mcT[(size_t)p * BS + bb] = part * (1.f / 64.f);
            }
        }
    } else {
        // h2 epilogue: packed bf16 stores, layout h2[b][f][p], 4 p per lane
        #pragma unroll
        for (int mi = 0; mi < 2; ++mi) {
            int p0 = pb + mi * 16 + g4 * 4;
            #pragma unroll
            for (int nj = 0; nj < 4; ++nj) {
                int f = nj * 16 + fr;
                uint2 pk;
                pk.x = pkbf(lrelu(acc[mi][nj][0]), lrelu(acc[mi][nj][1]));
                pk.y = pkbf(lrelu(acc[mi][nj][2]), lrelu(acc[mi][nj][3]));
                *(uint2*)&h2[(((size_t)bb * 64 + f) << 10) + p0] = pk;
            }
        }
    }
}

// ---------------------------------------------------------------------------
// Kernel 2: softmax over batch per pixel; mcT[p][b] -> attnN[b][p]  (R9 form)
// ---------------------------------------------------------------------------
__global__ __launch_bounds__(256) void softmax_b(
    const float* __restrict__ mcT, float* __restrict__ attnN)
{
    int p = blockIdx.x, t = threadIdx.x;
    float v = mcT[(size_t)p * BS + t];
    float m = v;
    #pragma unroll
    for (int o = 32; o > 0; o >>= 1) m = fmaxf(m, __shfl_xor(m, o));
    __shared__ float r1[4], r2[4];
    int w = t >> 6, lz = t & 63;
    if (lz == 0) r1[w] = m;
    __syncthreads();
    m = fmaxf(fmaxf(r1[0], r1[1]), fmaxf(r1[2], r1[3]));
    float e = expf(v - m);
    float s = e;
    #pragma unroll
    for (int o = 32; o > 0; o >>= 1) s += __shfl_xor(s, o);
    if (lz == 0) r2[w] = s;
    __syncthreads();
    s = r2[0] + r2[1] + r2[2] + r2[3];
    attnN[(size_t)t * PIX + p] = e / s;
}

// ---------------------------------------------------------------------------
// Kernel 3: neighbour + blend, 1024 threads (16 waves).  (R9 form)
// ---------------------------------------------------------------------------
__global__ __launch_bounds__(1024) void neighbour_k(
    const unsigned short* __restrict__ h2, const float* __restrict__ attnN,
    const float* __restrict__ chalf, float* __restrict__ out)
{
    int b = blockIdx.x, tid = threadIdx.x;
    int l = tid & 63, w = tid >> 6;       // 16 waves
    __shared__ float att[PIX];
    if (tid < PIX) att[tid] = attnN[(size_t)b * PIX + tid];
    __syncthreads();

    float av[16];
    #pragma unroll
    for (int i = 0; i < 8; ++i) av[i]     = att[l * 8 + i];
    #pragma unroll
    for (int i = 0; i < 8; ++i) av[8 + i] = att[512 + l * 8 + i];

    const unsigned short* hb = h2 + ((size_t)b * 64) * 1024;
    #pragma unroll
    for (int j = 0; j < 4; ++j) {
        int f = w * 4 + j;
        const unsigned short* hf = hb + (size_t)f * 1024;
        bf16x8 h0 = *(const bf16x8*)&hf[l * 8];
        bf16x8 h1 = *(const bf16x8*)&hf[512 + l * 8];
        float acc = 0.f;
        #pragma unroll
        for (int i = 0; i < 8; ++i) acc += bf2f(h0[i]) * av[i];
        #pragma unroll
        for (int i = 0; i < 8; ++i) acc += bf2f(h1[i]) * av[8 + i];
        #pragma unroll
        for (int o = 32; o > 0; o >>= 1) acc += __shfl_xor(acc, o);
        if (l == 0)
            out[b * FEAT + f] = chalf[b * FEAT + f] + (1.f - BETA) * acc;
    }
}

// ---------------------------------------------------------------------------
extern "C" void kernel_launch(void* const* d_in, const int* in_sizes, int n_in,
                              void* d_out, int out_size, void* d_ws, size_t ws_size,
                              hipStream_t stream)
{
    const float* x  = (const float*)d_in[0];
    const float* Wk = (const float*)d_in[1];
    const float* Wv = (const float*)d_in[2];
    const float* Wn = (const float*)d_in[3];
    float* out = (float*)d_out;

    float* ws    = (float*)d_ws;
    float* c1    = ws;                                   // 16384 f
    float* chalf = ws + 16384;                           // 16384 f
    float* mcT   = ws + 32768;                           // 262144 f  [p][b]
    float* attnN = ws + 294912;                          // 262144 f  [b][p]
    unsigned short* Wb = (unsigned short*)(ws + 557056); // 28672 u16
    unsigned short* h2 = (unsigned short*)((char*)d_ws + 2285568); // 33.5 MB

    prep_k     <<<270,  256, 0, stream>>>(x, Wk, Wv, Wn, Wb, c1, chalf);
    gemm_direct<<<4096, 256, 0, stream>>>(x, Wb, c1, mcT, h2);
    softmax_b  <<<PIX,  256, 0, stream>>>(mcT, attnN);
    neighbour_k<<<BS, 1024, 0, stream>>>(h2, attnN, chalf, out);
}

// Round 17
// 62.206 us; speedup vs baseline: 1.3026x; 1.3026x over previous
//
#include <hip/hip_runtime.h>
#include <hip/hip_bf16.h>

#define BS    256
#define PIX   1024
#define CBAND 200
#define NK    7            // K-steps of 32 (K 200 -> 224; tail k>=200 hits B=0)
#define FEAT  64
#define ALPHA 0.2f
#define BETA  0.5f
#define TROWS 32           // rows per K-tile
#define NTILE 16           // tiles per block (512 rows/block, grid 512 = 2/CU)
#define XSTR  232          // LDS row stride in bf16 (464 B -> uniform-bank b128)

typedef __attribute__((ext_vector_type(8))) short bf16x8;   // MFMA A/B fragment
typedef __attribute__((ext_vector_type(4))) float f32x4;    // MFMA C/D fragment

__device__ __forceinline__ float lrelu(float v) { return v >= 0.f ? v : ALPHA * v; }
__device__ __forceinline__ float bf2f(short s) {
    unsigned int u = ((unsigned int)(unsigned short)s) << 16;
    return __uint_as_float(u);
}
__device__ __forceinline__ unsigned int pkbf(float a, float b) {
    __hip_bfloat162 t = __float22bfloat162_rn(make_float2(a, b));
    return *(unsigned int*)&t;
}

// lgkm-only tile barrier (R15-validated: null-to-slightly-better vs
// __syncthreads; lets prefetch loads/h2 stores stay in flight).
__device__ __forceinline__ void tile_barrier() {
    asm volatile("s_waitcnt lgkmcnt(0)" ::: "memory");
    __builtin_amdgcn_s_barrier();
}

// ---------------------------------------------------------------------------
// Kernel 0 (fused prep), 256 threads/block.  (unchanged)
// ---------------------------------------------------------------------------
__global__ __launch_bounds__(256) void prep_k(
    const float* __restrict__ x, const float* __restrict__ Wk,
    const float* __restrict__ Wv, const float* __restrict__ Wn,
    unsigned short* __restrict__ Wb, float* __restrict__ c1,
    float* __restrict__ chalf)
{
    const int tid = threadIdx.x;
    if (blockIdx.x < 14) {
        int bid2 = blockIdx.x * 4 + (tid >> 6);   // 0..55
        int l  = tid & 63;
        int nf = bid2 & 7;
        int ks = bid2 >> 3;
        int c  = nf * 16 + (l & 15);
        int k0 = ks * 32 + (l >> 4) * 8;
        __attribute__((aligned(16))) unsigned short o[8];
        #pragma unroll
        for (int i = 0; i < 8; ++i) {
            int k = k0 + i;
            float w = 0.f;
            if (k < CBAND) w = (c < 64) ? Wk[k * 64 + c] : Wv[k * 64 + (c - 64)];
            unsigned int u = __float_as_uint(w);
            u += 0x7FFFu + ((u >> 16) & 1u);      // RNE to bf16
            o[i] = (unsigned short)(u >> 16);
        }
        *(uint4*)&Wb[((size_t)bid2 * 64 + l) * 8] = *(uint4*)o;
        return;
    }
    __shared__ float xr[CBAND];
    __shared__ float part[2][4][FEAT];
    __shared__ float c2s[FEAT];
    int b = blockIdx.x - 14;
    int f = tid & 63, q = tid >> 6;
    const float* xc = x + (size_t)b * (PIX * CBAND) + (16 * 32 + 16) * CBAND;
    for (int c = tid; c < CBAND; c += 256) xr[c] = xc[c];
    __syncthreads();
    float a1 = 0.f, a2 = 0.f;
    #pragma unroll 5
    for (int c = q * 50; c < q * 50 + 50; ++c) {
        float xv = xr[c];
        a1 += xv * Wk[c * FEAT + f];
        a2 += xv * Wv[c * FEAT + f];
    }
    part[0][q][f] = a1;
    part[1][q][f] = a2;
    __syncthreads();
    if (tid < FEAT) {
        float s1 = part[0][0][f] + part[0][1][f] + part[0][2][f] + part[0][3][f];
        float s2 = part[1][0][f] + part[1][1][f] + part[1][2][f] + part[1][3][f];
        c1[b * FEAT + f] = lrelu(s1);
        c2s[f] = lrelu(s2);
    }
    __syncthreads();
    if (tid < FEAT) {
        float a3 = 0.f;
        #pragma unroll 8
        for (int g = 0; g < FEAT; ++g) a3 += c2s[g] * Wn[f * FEAT + g];
        chalf[b * FEAT + f] = BETA * lrelu(a3);
    }
}

// ---------------------------------------------------------------------------
// Kernel 1: MFMA GEMM — R15 structure with NTILE=16, grid 512 (= exactly
// 2 blocks/CU, single generation). Block-invariant bq/c1 prologue paid once
// per 512 rows (was per 128); no generational dispatch churn.
// ---------------------------------------------------------------------------
__global__ __launch_bounds__(256, 2) void gemm_mfma(
    const float* __restrict__ x, const unsigned short* __restrict__ Wb,
    const float* __restrict__ c1, float* __restrict__ mcT,
    unsigned short* __restrict__ h2)
{
    __shared__ unsigned short xs[2][TROWS * XSTR];   // 2 x 14848 B
    __shared__ float c1s[FEAT];
    __shared__ float hpart[2][2][TROWS];

    const int tid = threadIdx.x;
    const int l   = tid & 63;
    const int w   = tid >> 6;
    const int bb  = blockIdx.x >> 1;              // 2 blocks per batch
    const int pbase = (blockIdx.x & 1) * (TROWS * NTILE);   // 0 or 512
    const size_t row0 = (size_t)blockIdx.x * (TROWS * NTILE);

    if (tid < 128) {                              // zero k-tail [200,232)
        int r = tid >> 2, q = tid & 3;
        *(uint4*)&xs[0][r * XSTR + 200 + q * 8] = make_uint4(0, 0, 0, 0);
        *(uint4*)&xs[1][r * XSTR + 200 + q * 8] = make_uint4(0, 0, 0, 0);
    }
    if (tid < FEAT) c1s[tid] = c1[bb * FEAT + tid];

    const bf16x8* wbv = (const bf16x8*)Wb;
    const int nf0 = 2 * w;
    bf16x8 bq[NK][2];
    #pragma unroll
    for (int ks = 0; ks < NK; ++ks)
        #pragma unroll
        for (int nj = 0; nj < 2; ++nj)
            bq[ks][nj] = wbv[(ks * 8 + nf0 + nj) * 64 + l];

    int rowj[4], c8j[4];
    #pragma unroll
    for (int j = 0; j < 4; ++j) {
        int u = tid + j * 256;
        rowj[j] = u / 25;
        c8j[j]  = u - rowj[j] * 25;
    }
    const bool has3 = (tid < 32);

    float4 sreg[4][2];
    auto loadtile = [&](int t) {
        const float* g = x + (row0 + (size_t)t * TROWS) * CBAND;
        #pragma unroll
        for (int j = 0; j < 4; ++j) {
            if (j < 3 || has3) {
                const float4* p = (const float4*)(g + rowj[j] * CBAND + c8j[j] * 8);
                sreg[j][0] = p[0];
                sreg[j][1] = p[1];
            }
        }
    };
    auto writetile = [&](int t) {
        unsigned short* d = xs[t & 1];
        #pragma unroll
        for (int j = 0; j < 4; ++j) {
            if (j < 3 || has3) {
                uint4 pk;
                pk.x = pkbf(sreg[j][0].x, sreg[j][0].y);
                pk.y = pkbf(sreg[j][0].z, sreg[j][0].w);
                pk.z = pkbf(sreg[j][1].x, sreg[j][1].y);
                pk.w = pkbf(sreg[j][1].z, sreg[j][1].w);
                *(uint4*)&d[rowj[j] * XSTR + c8j[j] * 8] = pk;
            }
        }
    };

    const int fr = l & 15;
    const int g4 = l >> 4;

    loadtile(0);
    writetile(0);
    loadtile(1);
    __syncthreads();                              // prologue: full sync once

    // h1 waves: hoist this wave's c1 slice to 8 regs.
    float c1r[2][4];
    if (w < 2) {
        #pragma unroll
        for (int nj = 0; nj < 2; ++nj)
            #pragma unroll
            for (int r = 0; r < 4; ++r)
                c1r[nj][r] = c1s[(nf0 + nj) * 16 + g4 * 4 + r];
    }

    for (int t = 0; t < NTILE; ++t) {
        const unsigned short* xb = xs[t & 1];
        f32x4 acc[2][2];
        #pragma unroll
        for (int mi = 0; mi < 2; ++mi)
            #pragma unroll
            for (int nj = 0; nj < 2; ++nj) acc[mi][nj] = (f32x4){0.f, 0.f, 0.f, 0.f};

        if (w < 2) {
            // h1 waves: SWAPPED operands -> D[f(reg)][p(lane)]
            #pragma unroll
            for (int ks = 0; ks < NK; ++ks) {
                bf16x8 a0 = *(const bf16x8*)&xb[fr * XSTR + ks * 32 + g4 * 8];
                bf16x8 a1 = *(const bf16x8*)&xb[(fr + 16) * XSTR + ks * 32 + g4 * 8];
                #pragma unroll
                for (int nj = 0; nj < 2; ++nj) {
                    acc[0][nj] = __builtin_amdgcn_mfma_f32_16x16x32_bf16(bq[ks][nj], a0, acc[0][nj], 0, 0, 0);
                    acc[1][nj] = __builtin_amdgcn_mfma_f32_16x16x32_bf16(bq[ks][nj], a1, acc[1][nj], 0, 0, 0);
                }
            }
        } else {
            // h2 waves: unswapped -> D[p(reg)][f(lane)]
            #pragma unroll
            for (int ks = 0; ks < NK; ++ks) {
                bf16x8 a0 = *(const bf16x8*)&xb[fr * XSTR + ks * 32 + g4 * 8];
                bf16x8 a1 = *(const bf16x8*)&xb[(fr + 16) * XSTR + ks * 32 + g4 * 8];
                #pragma unroll
                for (int nj = 0; nj < 2; ++nj) {
                    acc[0][nj] = __builtin_amdgcn_mfma_f32_16x16x32_bf16(a0, bq[ks][nj], acc[0][nj], 0, 0, 0);
                    acc[1][nj] = __builtin_amdgcn_mfma_f32_16x16x32_bf16(a1, bq[ks][nj], acc[1][nj], 0, 0, 0);
                }
            }
        }

        if (t + 1 < NTILE) writetile(t + 1);
        if (t + 2 < NTILE) loadtile(t + 2);

        if (w < 2) {
            // h1 epilogue: 8 in-reg FMAs + 2 shfl_xor (16,32) per mi-frag
            #pragma unroll
            for (int mi = 0; mi < 2; ++mi) {
                float part = 0.f;
                #pragma unroll
                for (int nj = 0; nj < 2; ++nj)
                    #pragma unroll
                    for (int r = 0; r < 4; ++r)
                        part += lrelu(acc[mi][nj][r]) * c1r[nj][r];
                part += __shfl_xor(part, 16);
                part += __shfl_xor(part, 32);
                if (g4 == 0) hpart[t & 1][w][mi * 16 + fr] = part;
            }
        } else {
            // h2 epilogue: store lrelu as bf16, layout h2[b][f][p], 4 p/lane
            #pragma unroll
            for (int mi = 0; mi < 2; ++mi) {
                int p0 = pbase + t * TROWS + mi * 16 + g4 * 4;
                #pragma unroll
                for (int nj = 0; nj < 2; ++nj) {
                    int f = (nf0 + nj - 4) * 16 + fr;
                    uint2 pk;
                    pk.x = pkbf(lrelu(acc[mi][nj][0]), lrelu(acc[mi][nj][1]));
                    pk.y = pkbf(lrelu(acc[mi][nj][2]), lrelu(acc[mi][nj][3]));
                    *(uint2*)&h2[(((size_t)bb * 64 + f) << 10) + p0] = pk;
                }
            }
        }

        tile_barrier();                           // lgkm-only: no vmcnt drain

        if (w == 3 && l < TROWS) {                // combine tile t's h1 halves
            int p = pbase + t * TROWS + l;
            float v = (hpart[t & 1][0][l] + hpart[t & 1][1][l]) * (1.f / 64.f);
            mcT[(size_t)p * BS + bb] = v;
        }
    }
}

// ---------------------------------------------------------------------------
// Kernel 2: softmax over batch per pixel; mcT[p][b] -> attnN[b][p]  (unchanged)
// ---------------------------------------------------------------------------
__global__ __launch_bounds__(256) void softmax_b(
    const float* __restrict__ mcT, float* __restrict__ attnN)
{
    int p = blockIdx.x, t = threadIdx.x;
    float v = mcT[(size_t)p * BS + t];
    float m = v;
    #pragma unroll
    for (int o = 32; o > 0; o >>= 1) m = fmaxf(m, __shfl_xor(m, o));
    __shared__ float r1[4], r2[4];
    int w = t >> 6, lz = t & 63;
    if (lz == 0) r1[w] = m;
    __syncthreads();
    m = fmaxf(fmaxf(r1[0], r1[1]), fmaxf(r1[2], r1[3]));
    float e = expf(v - m);
    float s = e;
    #pragma unroll
    for (int o = 32; o > 0; o >>= 1) s += __shfl_xor(s, o);
    if (lz == 0) r2[w] = s;
    __syncthreads();
    s = r2[0] + r2[1] + r2[2] + r2[3];
    attnN[(size_t)t * PIX + p] = e / s;
}

// ---------------------------------------------------------------------------
// Kernel 3: neighbour + blend, 1024 threads (16 waves).  (unchanged)
// ---------------------------------------------------------------------------
__global__ __launch_bounds__(1024) void neighbour_k(
    const unsigned short* __restrict__ h2, const float* __restrict__ attnN,
    const float* __restrict__ chalf, float* __restrict__ out)
{
    int b = blockIdx.x, tid = threadIdx.x;
    int l = tid & 63, w = tid >> 6;       // 16 waves
    __shared__ float att[PIX];
    if (tid < PIX) att[tid] = attnN[(size_t)b * PIX + tid];
    __syncthreads();

    float av[16];
    #pragma unroll
    for (int i = 0; i < 8; ++i) av[i]     = att[l * 8 + i];
    #pragma unroll
    for (int i = 0; i < 8; ++i) av[8 + i] = att[512 + l * 8 + i];

    const unsigned short* hb = h2 + ((size_t)b * 64) * 1024;
    #pragma unroll
    for (int j = 0; j < 4; ++j) {
        int f = w * 4 + j;
        const unsigned short* hf = hb + (size_t)f * 1024;
        bf16x8 h0 = *(const bf16x8*)&hf[l * 8];
        bf16x8 h1 = *(const bf16x8*)&hf[512 + l * 8];
        float acc = 0.f;
        #pragma unroll
        for (int i = 0; i < 8; ++i) acc += bf2f(h0[i]) * av[i];
        #pragma unroll
        for (int i = 0; i < 8; ++i) acc += bf2f(h1[i]) * av[8 + i];
        #pragma unroll
        for (int o = 32; o > 0; o >>= 1) acc += __shfl_xor(acc, o);
        if (l == 0)
            out[b * FEAT + f] = chalf[b * FEAT + f] + (1.f - BETA) * acc;
    }
}

// ---------------------------------------------------------------------------
extern "C" void kernel_launch(void* const* d_in, const int* in_sizes, int n_in,
                              void* d_out, int out_size, void* d_ws, size_t ws_size,
                              hipStream_t stream)
{
    const float* x  = (const float*)d_in[0];
    const float* Wk = (const float*)d_in[1];
    const float* Wv = (const float*)d_in[2];
    const float* Wn = (const float*)d_in[3];
    float* out = (float*)d_out;

    float* ws    = (float*)d_ws;
    float* c1    = ws;                                   // 16384 f
    float* chalf = ws + 16384;                           // 16384 f
    float* mcT   = ws + 32768;                           // 262144 f  [p][b]
    float* attnN = ws + 294912;                          // 262144 f  [b][p]
    unsigned short* Wb = (unsigned short*)(ws + 557056); // 28672 u16
    unsigned short* h2 = (unsigned short*)((char*)d_ws + 2285568); // 33.5 MB

    prep_k   <<<270,  256, 0, stream>>>(x, Wk, Wv, Wn, Wb, c1, chalf);
    gemm_mfma<<<512,  256, 0, stream>>>(x, Wb, c1, mcT, h2);
    softmax_b<<<PIX,  256, 0, stream>>>(mcT, attnN);
    neighbour_k<<<BS, 1024, 0, stream>>>(h2, attnN, chalf, out);
}

// Round 18
// 58.284 us; speedup vs baseline: 1.3902x; 1.0673x over previous
//
#include <hip/hip_runtime.h>
#include <hip/hip_bf16.h>

#define BS    256
#define PIX   1024
#define CBAND 200
#define NK    7            // K-steps of 32 (K 200 -> 224; tail k>=200 hits B=0)
#define FEAT  64
#define ALPHA 0.2f
#define BETA  0.5f
#define TROWS 32           // rows per K-tile
#define NTILE 16           // tiles per block (512 rows/block, grid 512 = 2/CU)
#define XSTR  232          // LDS row stride in bf16 (464 B -> uniform-bank b128)

typedef __attribute__((ext_vector_type(8))) short bf16x8;   // MFMA A/B fragment
typedef __attribute__((ext_vector_type(4))) float f32x4;    // MFMA C/D fragment
typedef __attribute__((ext_vector_type(2))) float f32x2;    // fp8 unpack pair

__device__ __forceinline__ float lrelu(float v) { return v >= 0.f ? v : ALPHA * v; }
__device__ __forceinline__ unsigned int pkbf(float a, float b) {
    __hip_bfloat162 t = __float22bfloat162_rn(make_float2(a, b));
    return *(unsigned int*)&t;
}

// lgkm-only tile barrier (R15-validated).
__device__ __forceinline__ void tile_barrier() {
    asm volatile("s_waitcnt lgkmcnt(0)" ::: "memory");
    __builtin_amdgcn_s_barrier();
}

// ---------------------------------------------------------------------------
// Kernel 0 (fused prep), 256 threads/block.  (unchanged)
// ---------------------------------------------------------------------------
__global__ __launch_bounds__(256) void prep_k(
    const float* __restrict__ x, const float* __restrict__ Wk,
    const float* __restrict__ Wv, const float* __restrict__ Wn,
    unsigned short* __restrict__ Wb, float* __restrict__ c1,
    float* __restrict__ chalf)
{
    const int tid = threadIdx.x;
    if (blockIdx.x < 14) {
        int bid2 = blockIdx.x * 4 + (tid >> 6);   // 0..55
        int l  = tid & 63;
        int nf = bid2 & 7;
        int ks = bid2 >> 3;
        int c  = nf * 16 + (l & 15);
        int k0 = ks * 32 + (l >> 4) * 8;
        __attribute__((aligned(16))) unsigned short o[8];
        #pragma unroll
        for (int i = 0; i < 8; ++i) {
            int k = k0 + i;
            float w = 0.f;
            if (k < CBAND) w = (c < 64) ? Wk[k * 64 + c] : Wv[k * 64 + (c - 64)];
            unsigned int u = __float_as_uint(w);
            u += 0x7FFFu + ((u >> 16) & 1u);      // RNE to bf16
            o[i] = (unsigned short)(u >> 16);
        }
        *(uint4*)&Wb[((size_t)bid2 * 64 + l) * 8] = *(uint4*)o;
        return;
    }
    __shared__ float xr[CBAND];
    __shared__ float part[2][4][FEAT];
    __shared__ float c2s[FEAT];
    int b = blockIdx.x - 14;
    int f = tid & 63, q = tid >> 6;
    const float* xc = x + (size_t)b * (PIX * CBAND) + (16 * 32 + 16) * CBAND;
    for (int c = tid; c < CBAND; c += 256) xr[c] = xc[c];
    __syncthreads();
    float a1 = 0.f, a2 = 0.f;
    #pragma unroll 5
    for (int c = q * 50; c < q * 50 + 50; ++c) {
        float xv = xr[c];
        a1 += xv * Wk[c * FEAT + f];
        a2 += xv * Wv[c * FEAT + f];
    }
    part[0][q][f] = a1;
    part[1][q][f] = a2;
    __syncthreads();
    if (tid < FEAT) {
        float s1 = part[0][0][f] + part[0][1][f] + part[0][2][f] + part[0][3][f];
        float s2 = part[1][0][f] + part[1][1][f] + part[1][2][f] + part[1][3][f];
        c1[b * FEAT + f] = lrelu(s1);
        c2s[f] = lrelu(s2);
    }
    __syncthreads();
    if (tid < FEAT) {
        float a3 = 0.f;
        #pragma unroll 8
        for (int g = 0; g < FEAT; ++g) a3 += c2s[g] * Wn[f * FEAT + g];
        chalf[b * FEAT + f] = BETA * lrelu(a3);
    }
}

// ---------------------------------------------------------------------------
// Kernel 1: MFMA GEMM — R17 structure (NTILE=16, grid 512, lgkm barrier,
// swapped h1 epilogue). ONLY change: h2 stored as fp8-e4m3 (HW cvt_pk),
// halving the h2 write stream (33.5 -> 16.75 MB).
// ---------------------------------------------------------------------------
__global__ __launch_bounds__(256, 2) void gemm_mfma(
    const float* __restrict__ x, const unsigned short* __restrict__ Wb,
    const float* __restrict__ c1, float* __restrict__ mcT,
    unsigned char* __restrict__ h2)
{
    __shared__ unsigned short xs[2][TROWS * XSTR];   // 2 x 14848 B
    __shared__ float c1s[FEAT];
    __shared__ float hpart[2][2][TROWS];

    const int tid = threadIdx.x;
    const int l   = tid & 63;
    const int w   = tid >> 6;
    const int bb  = blockIdx.x >> 1;              // 2 blocks per batch
    const int pbase = (blockIdx.x & 1) * (TROWS * NTILE);   // 0 or 512
    const size_t row0 = (size_t)blockIdx.x * (TROWS * NTILE);

    if (tid < 128) {                              // zero k-tail [200,232)
        int r = tid >> 2, q = tid & 3;
        *(uint4*)&xs[0][r * XSTR + 200 + q * 8] = make_uint4(0, 0, 0, 0);
        *(uint4*)&xs[1][r * XSTR + 200 + q * 8] = make_uint4(0, 0, 0, 0);
    }
    if (tid < FEAT) c1s[tid] = c1[bb * FEAT + tid];

    const bf16x8* wbv = (const bf16x8*)Wb;
    const int nf0 = 2 * w;
    bf16x8 bq[NK][2];
    #pragma unroll
    for (int ks = 0; ks < NK; ++ks)
        #pragma unroll
        for (int nj = 0; nj < 2; ++nj)
            bq[ks][nj] = wbv[(ks * 8 + nf0 + nj) * 64 + l];

    int rowj[4], c8j[4];
    #pragma unroll
    for (int j = 0; j < 4; ++j) {
        int u = tid + j * 256;
        rowj[j] = u / 25;
        c8j[j]  = u - rowj[j] * 25;
    }
    const bool has3 = (tid < 32);

    float4 sreg[4][2];
    auto loadtile = [&](int t) {
        const float* g = x + (row0 + (size_t)t * TROWS) * CBAND;
        #pragma unroll
        for (int j = 0; j < 4; ++j) {
            if (j < 3 || has3) {
                const float4* p = (const float4*)(g + rowj[j] * CBAND + c8j[j] * 8);
                sreg[j][0] = p[0];
                sreg[j][1] = p[1];
            }
        }
    };
    auto writetile = [&](int t) {
        unsigned short* d = xs[t & 1];
        #pragma unroll
        for (int j = 0; j < 4; ++j) {
            if (j < 3 || has3) {
                uint4 pk;
                pk.x = pkbf(sreg[j][0].x, sreg[j][0].y);
                pk.y = pkbf(sreg[j][0].z, sreg[j][0].w);
                pk.z = pkbf(sreg[j][1].x, sreg[j][1].y);
                pk.w = pkbf(sreg[j][1].z, sreg[j][1].w);
                *(uint4*)&d[rowj[j] * XSTR + c8j[j] * 8] = pk;
            }
        }
    };

    const int fr = l & 15;
    const int g4 = l >> 4;

    loadtile(0);
    writetile(0);
    loadtile(1);
    __syncthreads();                              // prologue: full sync once

    // h1 waves: hoist this wave's c1 slice to 8 regs.
    float c1r[2][4];
    if (w < 2) {
        #pragma unroll
        for (int nj = 0; nj < 2; ++nj)
            #pragma unroll
            for (int r = 0; r < 4; ++r)
                c1r[nj][r] = c1s[(nf0 + nj) * 16 + g4 * 4 + r];
    }

    for (int t = 0; t < NTILE; ++t) {
        const unsigned short* xb = xs[t & 1];
        f32x4 acc[2][2];
        #pragma unroll
        for (int mi = 0; mi < 2; ++mi)
            #pragma unroll
            for (int nj = 0; nj < 2; ++nj) acc[mi][nj] = (f32x4){0.f, 0.f, 0.f, 0.f};

        if (w < 2) {
            // h1 waves: SWAPPED operands -> D[f(reg)][p(lane)]
            #pragma unroll
            for (int ks = 0; ks < NK; ++ks) {
                bf16x8 a0 = *(const bf16x8*)&xb[fr * XSTR + ks * 32 + g4 * 8];
                bf16x8 a1 = *(const bf16x8*)&xb[(fr + 16) * XSTR + ks * 32 + g4 * 8];
                #pragma unroll
                for (int nj = 0; nj < 2; ++nj) {
                    acc[0][nj] = __builtin_amdgcn_mfma_f32_16x16x32_bf16(bq[ks][nj], a0, acc[0][nj], 0, 0, 0);
                    acc[1][nj] = __builtin_amdgcn_mfma_f32_16x16x32_bf16(bq[ks][nj], a1, acc[1][nj], 0, 0, 0);
                }
            }
        } else {
            // h2 waves: unswapped -> D[p(reg)][f(lane)]
            #pragma unroll
            for (int ks = 0; ks < NK; ++ks) {
                bf16x8 a0 = *(const bf16x8*)&xb[fr * XSTR + ks * 32 + g4 * 8];
                bf16x8 a1 = *(const bf16x8*)&xb[(fr + 16) * XSTR + ks * 32 + g4 * 8];
                #pragma unroll
                for (int nj = 0; nj < 2; ++nj) {
                    acc[0][nj] = __builtin_amdgcn_mfma_f32_16x16x32_bf16(a0, bq[ks][nj], acc[0][nj], 0, 0, 0);
                    acc[1][nj] = __builtin_amdgcn_mfma_f32_16x16x32_bf16(a1, bq[ks][nj], acc[1][nj], 0, 0, 0);
                }
            }
        }

        if (t + 1 < NTILE) writetile(t + 1);
        if (t + 2 < NTILE) loadtile(t + 2);

        if (w < 2) {
            // h1 epilogue: 8 in-reg FMAs + 2 shfl_xor (16,32) per mi-frag
            #pragma unroll
            for (int mi = 0; mi < 2; ++mi) {
                float part = 0.f;
                #pragma unroll
                for (int nj = 0; nj < 2; ++nj)
                    #pragma unroll
                    for (int r = 0; r < 4; ++r)
                        part += lrelu(acc[mi][nj][r]) * c1r[nj][r];
                part += __shfl_xor(part, 16);
                part += __shfl_xor(part, 32);
                if (g4 == 0) hpart[t & 1][w][mi * 16 + fr] = part;
            }
        } else {
            // h2 epilogue: store lrelu as FP8-E4M3 (HW cvt, RNE), h2[b][f][p],
            // 4 consecutive p per lane -> one dword store.
            #pragma unroll
            for (int mi = 0; mi < 2; ++mi) {
                int p0 = pbase + t * TROWS + mi * 16 + g4 * 4;
                #pragma unroll
                for (int nj = 0; nj < 2; ++nj) {
                    int f = (nf0 + nj - 4) * 16 + fr;
                    unsigned int d = 0;
                    d = __builtin_amdgcn_cvt_pk_fp8_f32(
                            lrelu(acc[mi][nj][0]), lrelu(acc[mi][nj][1]), d, false);
                    d = __builtin_amdgcn_cvt_pk_fp8_f32(
                            lrelu(acc[mi][nj][2]), lrelu(acc[mi][nj][3]), d, true);
                    *(unsigned int*)&h2[(((size_t)bb * 64 + f) << 10) + p0] = d;
                }
            }
        }

        tile_barrier();                           // lgkm-only: no vmcnt drain

        if (w == 3 && l < TROWS) {                // combine tile t's h1 halves
            int p = pbase + t * TROWS + l;
            float v = (hpart[t & 1][0][l] + hpart[t & 1][1][l]) * (1.f / 64.f);
            mcT[(size_t)p * BS + bb] = v;
        }
    }
}

// ---------------------------------------------------------------------------
// Kernel 2: softmax over batch per pixel; mcT[p][b] -> attnN[b][p]  (unchanged)
// ---------------------------------------------------------------------------
__global__ __launch_bounds__(256) void softmax_b(
    const float* __restrict__ mcT, float* __restrict__ attnN)
{
    int p = blockIdx.x, t = threadIdx.x;
    float v = mcT[(size_t)p * BS + t];
    float m = v;
    #pragma unroll
    for (int o = 32; o > 0; o >>= 1) m = fmaxf(m, __shfl_xor(m, o));
    __shared__ float r1[4], r2[4];
    int w = t >> 6, lz = t & 63;
    if (lz == 0) r1[w] = m;
    __syncthreads();
    m = fmaxf(fmaxf(r1[0], r1[1]), fmaxf(r1[2], r1[3]));
    float e = expf(v - m);
    float s = e;
    #pragma unroll
    for (int o = 32; o > 0; o >>= 1) s += __shfl_xor(s, o);
    if (lz == 0) r2[w] = s;
    __syncthreads();
    s = r2[0] + r2[1] + r2[2] + r2[3];
    attnN[(size_t)t * PIX + p] = e / s;
}

// ---------------------------------------------------------------------------
// Kernel 3: neighbour + blend, 1024 threads (16 waves). h2 read as fp8-e4m3
// (HW cvt_pk_f32_fp8 unpack); 8 p values = one uint2 per lane per half.
// ---------------------------------------------------------------------------
__global__ __launch_bounds__(1024) void neighbour_k(
    const unsigned char* __restrict__ h2, const float* __restrict__ attnN,
    const float* __restrict__ chalf, float* __restrict__ out)
{
    int b = blockIdx.x, tid = threadIdx.x;
    int l = tid & 63, w = tid >> 6;       // 16 waves
    __shared__ float att[PIX];
    if (tid < PIX) att[tid] = attnN[(size_t)b * PIX + tid];
    __syncthreads();

    float av[16];
    #pragma unroll
    for (int i = 0; i < 8; ++i) av[i]     = att[l * 8 + i];
    #pragma unroll
    for (int i = 0; i < 8; ++i) av[8 + i] = att[512 + l * 8 + i];

    const unsigned char* hb = h2 + ((size_t)b * 64) * 1024;
    #pragma unroll
    for (int j = 0; j < 4; ++j) {
        int f = w * 4 + j;
        const unsigned char* hf = hb + (size_t)f * 1024;
        uint2 u0 = *(const uint2*)&hf[l * 8];         // p = l*8 .. +7
        uint2 u1 = *(const uint2*)&hf[512 + l * 8];   // p = 512+l*8 .. +7
        float acc = 0.f;
        {
            f32x2 q0 = __builtin_amdgcn_cvt_pk_f32_fp8(u0.x, false);
            f32x2 q1 = __builtin_amdgcn_cvt_pk_f32_fp8(u0.x, true);
            f32x2 q2 = __builtin_amdgcn_cvt_pk_f32_fp8(u0.y, false);
            f32x2 q3 = __builtin_amdgcn_cvt_pk_f32_fp8(u0.y, true);
            acc += q0[0] * av[0] + q0[1] * av[1] + q1[0] * av[2] + q1[1] * av[3];
            acc += q2[0] * av[4] + q2[1] * av[5] + q3[0] * av[6] + q3[1] * av[7];
        }
        {
            f32x2 q0 = __builtin_amdgcn_cvt_pk_f32_fp8(u1.x, false);
            f32x2 q1 = __builtin_amdgcn_cvt_pk_f32_fp8(u1.x, true);
            f32x2 q2 = __builtin_amdgcn_cvt_pk_f32_fp8(u1.y, false);
            f32x2 q3 = __builtin_amdgcn_cvt_pk_f32_fp8(u1.y, true);
            acc += q0[0] * av[8]  + q0[1] * av[9]  + q1[0] * av[10] + q1[1] * av[11];
            acc += q2[0] * av[12] + q2[1] * av[13] + q3[0] * av[14] + q3[1] * av[15];
        }
        #pragma unroll
        for (int o = 32; o > 0; o >>= 1) acc += __shfl_xor(acc, o);
        if (l == 0)
            out[b * FEAT + f] = chalf[b * FEAT + f] + (1.f - BETA) * acc;
    }
}

// ---------------------------------------------------------------------------
extern "C" void kernel_launch(void* const* d_in, const int* in_sizes, int n_in,
                              void* d_out, int out_size, void* d_ws, size_t ws_size,
                              hipStream_t stream)
{
    const float* x  = (const float*)d_in[0];
    const float* Wk = (const float*)d_in[1];
    const float* Wv = (const float*)d_in[2];
    const float* Wn = (const float*)d_in[3];
    float* out = (float*)d_out;

    float* ws    = (float*)d_ws;
    float* c1    = ws;                                   // 16384 f
    float* chalf = ws + 16384;                           // 16384 f
    float* mcT   = ws + 32768;                           // 262144 f  [p][b]
    float* attnN = ws + 294912;                          // 262144 f  [b][p]
    unsigned short* Wb = (unsigned short*)(ws + 557056); // 28672 u16
    unsigned char* h2 = (unsigned char*)((char*)d_ws + 2285568); // 16.75 MB fp8

    prep_k   <<<270,  256, 0, stream>>>(x, Wk, Wv, Wn, Wb, c1, chalf);
    gemm_mfma<<<512,  256, 0, stream>>>(x, Wb, c1, mcT, h2);
    softmax_b<<<PIX,  256, 0, stream>>>(mcT, attnN);
    neighbour_k<<<BS, 1024, 0, stream>>>(h2, attnN, chalf, out);
}